// Round 2
// baseline (162.051 us; speedup 1.0000x reference)
//
#include <hip/hip_runtime.h>
#include <hip/hip_bf16.h>

// Triangle attention (start) — N=256, C=128, H=4, D=32, f16 MFMA pipeline.
// R1: operand-swapped MFMA epilogues (lane holds 4 consecutive out cols ->
//     packed 8B/16B stores), LayerNorm fused into proj kernel.

typedef _Float16 half8 __attribute__((ext_vector_type(8)));
typedef _Float16 half4 __attribute__((ext_vector_type(4)));
typedef float floatx4 __attribute__((ext_vector_type(4)));

#define NN 256
#define CC 128
#define HH 4
#define DD 32
#define NR (NN*NN)          // 65536 rows
#define LN_EPS 1e-5f
#define PSLD 264            // LDS row pad: 264 f16 = 528B -> bank step 4

// ---------------- Stage 1: weight prep ----------------
__global__ __launch_bounds__(256) void prep_weights(
    const float* __restrict__ Wq, const float* __restrict__ Wk,
    const float* __restrict__ Wv, const float* __restrict__ Wg,
    const float* __restrict__ Wo, const float* __restrict__ Wb,
    _Float16* __restrict__ WqT, _Float16* __restrict__ WkT,
    _Float16* __restrict__ WvT, _Float16* __restrict__ WgT,
    _Float16* __restrict__ WoT, _Float16* __restrict__ WbT)
{
    int id = blockIdx.x * 256 + threadIdx.x;
    if (id < 5 * 16384) {
        int m = id / 16384, e = id % 16384;
        int n = e >> 7, c = e & 127;
        const float* src = (m==0)?Wq:(m==1)?Wk:(m==2)?Wv:(m==3)?Wg:Wo;
        _Float16* dst    = (m==0)?WqT:(m==1)?WkT:(m==2)?WvT:(m==3)?WgT:WoT;
        dst[n*128 + c] = (_Float16)src[c*128 + n];
    } else {
        int e = id - 5*16384;   // WbT padded to [16][128]
        if (e < 16*128) {
            int n = e >> 7, c = e & 127;
            WbT[n*128 + c] = (n < HH) ? (_Float16)Wb[c*HH + n] : (_Float16)0.f;
        }
    }
}

// ---------------- Stage 2+3: fused LayerNorm + projections ----------------
// Wave computes a 16-row tile. z-rows are the B operand; weights are A.
// D[m][n]: n = lane&15 = z-row, m = (lane>>4)*4+reg = 4 consecutive out cols.
__global__ __launch_bounds__(256) void proj_kernel(
    const float* __restrict__ pair, const float* __restrict__ ln_scale,
    const float* __restrict__ ln_bias,
    const _Float16* __restrict__ WqT, const _Float16* __restrict__ WkT,
    const _Float16* __restrict__ WvT, const _Float16* __restrict__ WgT,
    const _Float16* __restrict__ WbT, const float* __restrict__ bg,
    _Float16* __restrict__ qh, _Float16* __restrict__ kh,
    _Float16* __restrict__ vh, _Float16* __restrict__ gh,
    float* __restrict__ biasF)
{
    int wave = threadIdx.x >> 6, lane = threadIdx.x & 63;
    int mtile = blockIdx.x * 4 + wave;          // 16-row tile of 65536 rows
    int lr = lane & 15, lg = lane >> 4;
    size_t row = (size_t)mtile*16 + lr;

    // ---- load 32 pair elems of this lane's row, LN stats ----
    float xv[4][8];
    float s = 0.f, ss = 0.f;
    #pragma unroll
    for (int ks = 0; ks < 4; ++ks) {
        const float* pr = &pair[row*CC + ks*32 + lg*8];
        float4 a = *(const float4*)pr;
        float4 b = *(const float4*)(pr + 4);
        xv[ks][0]=a.x; xv[ks][1]=a.y; xv[ks][2]=a.z; xv[ks][3]=a.w;
        xv[ks][4]=b.x; xv[ks][5]=b.y; xv[ks][6]=b.z; xv[ks][7]=b.w;
        s  += a.x+a.y+a.z+a.w + b.x+b.y+b.z+b.w;
        ss += a.x*a.x+a.y*a.y+a.z*a.z+a.w*a.w + b.x*b.x+b.y*b.y+b.z*b.z+b.w*b.w;
    }
    s  += __shfl_xor(s, 16);  s  += __shfl_xor(s, 32);
    ss += __shfl_xor(ss, 16); ss += __shfl_xor(ss, 32);
    float mu   = s * (1.f/128.f);
    float var  = ss * (1.f/128.f) - mu*mu;
    float rstd = rsqrtf(var + LN_EPS);

    half8 zfrag[4];
    #pragma unroll
    for (int ks = 0; ks < 4; ++ks) {
        const float* sc = &ln_scale[ks*32 + lg*8];
        const float* bi = &ln_bias[ks*32 + lg*8];
        #pragma unroll
        for (int e = 0; e < 8; ++e)
            zfrag[ks][e] = (_Float16)((xv[ks][e] - mu) * rstd * sc[e] + bi[e]);
    }

    const _Float16* Ws[4]   = {WqT, WkT, WvT, WgT};
    _Float16*       outs[4] = {qh, kh, vh, gh};

    #pragma unroll
    for (int p = 0; p < 4; ++p) {
        const _Float16* WT = Ws[p];
        floatx4 acc[8];
        #pragma unroll
        for (int nt = 0; nt < 8; ++nt) acc[nt] = (floatx4){0.f,0.f,0.f,0.f};
        #pragma unroll
        for (int nt = 0; nt < 8; ++nt) {
            #pragma unroll
            for (int ks = 0; ks < 4; ++ks) {
                half8 w = *(const half8*)&WT[(nt*16 + lr)*128 + ks*32 + lg*8];
                acc[nt] = __builtin_amdgcn_mfma_f32_16x16x32_f16(w, zfrag[ks], acc[nt], 0, 0, 0);
            }
        }
        #pragma unroll
        for (int nt = 0; nt < 8; ++nt) {
            int col = nt*16 + lg*4;
            half4 pk;
            if (p == 3) {
                float4 b4 = *(const float4*)&bg[col];
                pk[0] = (_Float16)(1.f / (1.f + __expf(-(acc[nt][0] + b4.x))));
                pk[1] = (_Float16)(1.f / (1.f + __expf(-(acc[nt][1] + b4.y))));
                pk[2] = (_Float16)(1.f / (1.f + __expf(-(acc[nt][2] + b4.z))));
                pk[3] = (_Float16)(1.f / (1.f + __expf(-(acc[nt][3] + b4.w))));
            } else {
                float sc2 = (p == 0) ? 0.17677669529663687f : 1.f;  // 1/sqrt(32)
                #pragma unroll
                for (int r = 0; r < 4; ++r) pk[r] = (_Float16)(acc[nt][r] * sc2);
            }
            *(half4*)&outs[p][row*CC + col] = pk;
        }
    }

    // pair bias: z @ Wb (WbT padded to 16 rows; rows >= 4 are zero)
    floatx4 acc2 = (floatx4){0.f,0.f,0.f,0.f};
    #pragma unroll
    for (int ks = 0; ks < 4; ++ks) {
        half8 w = *(const half8*)&WbT[lr*128 + ks*32 + lg*8];
        acc2 = __builtin_amdgcn_mfma_f32_16x16x32_f16(w, zfrag[ks], acc2, 0, 0, 0);
    }
    if (lg == 0) {       // lanes 0..15 hold h = 0..3 for z-row = lr
        #pragma unroll
        for (int r = 0; r < 4; ++r)
            biasF[(size_t)r*NR + row] = acc2[r];   // biasF[h][a*256+b]
    }
}

// ---------------- Stage 4: attention per (h, i) ----------------
__global__ __launch_bounds__(256) void attn_kernel(
    const _Float16* __restrict__ qh, const _Float16* __restrict__ kh,
    const _Float16* __restrict__ vh, const _Float16* __restrict__ gh,
    const float* __restrict__ biasF, _Float16* __restrict__ oh)
{
    __shared__ _Float16 Vt[DD][PSLD];        // V transposed: Vt[d][k]
    __shared__ _Float16 Ps[4][16][PSLD];     // per-wave P tile

    int ib = blockIdx.x;       // i (row index of pair)
    int h  = blockIdx.y;       // head
    int tid = threadIdx.x;
    int wave = tid >> 6, lane = tid & 63;
    int lr = lane & 15, lg = lane >> 4;
    size_t rbase = (size_t)ib * NN;

    // stage V transposed into LDS
    {
        int d = tid & 31;
        for (int kk = tid >> 5; kk < NN; kk += 8)
            Vt[d][kk] = vh[(rbase + kk)*CC + h*DD + d];
    }
    __syncthreads();

    for (int jt = wave; jt < 16; jt += 4) {
        // ---- S = Q K^T ----
        half8 aq = *(const half8*)&qh[(rbase + jt*16 + lr)*CC + h*DD + lg*8];
        floatx4 zero = (floatx4){0.f,0.f,0.f,0.f};
        floatx4 sacc[16];
        #pragma unroll
        for (int nt = 0; nt < 16; ++nt) {
            half8 bk = *(const half8*)&kh[(rbase + nt*16 + lr)*CC + h*DD + lg*8];
            sacc[nt] = __builtin_amdgcn_mfma_f32_16x16x32_f16(aq, bk, zero, 0, 0, 0);
        }

        // ---- + bias, row max ----   (lane: j = jt*16+lg*4+r, k = nt*16+lr)
        float m[4];
        #pragma unroll
        for (int r = 0; r < 4; ++r) m[r] = -1e30f;
        #pragma unroll
        for (int nt = 0; nt < 16; ++nt) {
            #pragma unroll
            for (int r = 0; r < 4; ++r) {
                int j = jt*16 + lg*4 + r;
                sacc[nt][r] += biasF[(size_t)h*NR + j*NN + nt*16 + lr];
                m[r] = fmaxf(m[r], sacc[nt][r]);
            }
        }
        #pragma unroll
        for (int r = 0; r < 4; ++r) {
            #pragma unroll
            for (int off = 1; off < 16; off <<= 1)
                m[r] = fmaxf(m[r], __shfl_xor(m[r], off));
        }

        // ---- exp + row sum ----
        float ssum[4] = {0.f, 0.f, 0.f, 0.f};
        #pragma unroll
        for (int nt = 0; nt < 16; ++nt) {
            #pragma unroll
            for (int r = 0; r < 4; ++r) {
                float p = __expf(sacc[nt][r] - m[r]);
                sacc[nt][r] = p;
                ssum[r] += p;
            }
        }
        #pragma unroll
        for (int r = 0; r < 4; ++r) {
            #pragma unroll
            for (int off = 1; off < 16; off <<= 1)
                ssum[r] += __shfl_xor(ssum[r], off);
            ssum[r] = 1.f / ssum[r];
        }

        // ---- normalized P -> LDS (A-row layout: Ps[j_local][k]) ----
        #pragma unroll
        for (int nt = 0; nt < 16; ++nt) {
            #pragma unroll
            for (int r = 0; r < 4; ++r)
                Ps[wave][lg*4 + r][nt*16 + lr] = (_Float16)(sacc[nt][r] * ssum[r]);
        }

        // ---- O = P V, operand-swapped: A = Vt rows (d), B = Ps rows (j) ----
        // D[m=d][n=j]: lane j = lr, d = nt2*16 + lg*4 + reg (4 consecutive)
        floatx4 oacc[2];
        oacc[0] = zero; oacc[1] = zero;
        #pragma unroll
        for (int ks = 0; ks < 8; ++ks) {
            half8 bp = *(const half8*)&Ps[wave][lr][ks*32 + lg*8];
            #pragma unroll
            for (int nt2 = 0; nt2 < 2; ++nt2) {
                half8 av = *(const half8*)&Vt[nt2*16 + lr][ks*32 + lg*8];
                oacc[nt2] = __builtin_amdgcn_mfma_f32_16x16x32_f16(av, bp, oacc[nt2], 0, 0, 0);
            }
        }

        // ---- * gate, packed 8B store ----
        int j = jt*16 + lr;
        #pragma unroll
        for (int nt2 = 0; nt2 < 2; ++nt2) {
            size_t base = (rbase + j)*CC + h*DD + nt2*16 + lg*4;
            half4 g4 = *(const half4*)&gh[base];
            half4 pk;
            #pragma unroll
            for (int r = 0; r < 4; ++r)
                pk[r] = (_Float16)(oacc[nt2][r] * (float)g4[r]);
            *(half4*)&oh[base] = pk;
        }
    }
}

// ---------------- Stage 5: output projection ----------------
// Operand-swapped: A = WoT rows, B = O rows -> lane holds 4 consecutive f32
// output cols -> one dwordx4 store per nt tile.
__global__ __launch_bounds__(256) void out_kernel(
    const _Float16* __restrict__ oh, const _Float16* __restrict__ WoT,
    const float* __restrict__ bo, float* __restrict__ out)
{
    int wave = threadIdx.x >> 6, lane = threadIdx.x & 63;
    int mtile = blockIdx.x * 4 + wave;
    int lr = lane & 15, lg = lane >> 4;
    size_t row = (size_t)mtile*16 + lr;

    half8 ofrag[4];
    #pragma unroll
    for (int ks = 0; ks < 4; ++ks)
        ofrag[ks] = *(const half8*)&oh[row*CC + ks*32 + lg*8];

    floatx4 acc[8];
    #pragma unroll
    for (int nt = 0; nt < 8; ++nt) acc[nt] = (floatx4){0.f,0.f,0.f,0.f};
    #pragma unroll
    for (int nt = 0; nt < 8; ++nt) {
        #pragma unroll
        for (int ks = 0; ks < 4; ++ks) {
            half8 w = *(const half8*)&WoT[(nt*16 + lr)*128 + ks*32 + lg*8];
            acc[nt] = __builtin_amdgcn_mfma_f32_16x16x32_f16(w, ofrag[ks], acc[nt], 0, 0, 0);
        }
    }
    #pragma unroll
    for (int nt = 0; nt < 8; ++nt) {
        int col = nt*16 + lg*4;
        float4 b4 = *(const float4*)&bo[col];
        float4 res = {acc[nt][0] + b4.x, acc[nt][1] + b4.y,
                      acc[nt][2] + b4.z, acc[nt][3] + b4.w};
        *(float4*)&out[row*CC + col] = res;
    }
}

// ---------------- launch ----------------
extern "C" void kernel_launch(void* const* d_in, const int* in_sizes, int n_in,
                              void* d_out, int out_size, void* d_ws, size_t ws_size,
                              hipStream_t stream)
{
    const float* pair     = (const float*)d_in[0];
    const float* ln_scale = (const float*)d_in[1];
    const float* ln_bias  = (const float*)d_in[2];
    const float* Wq       = (const float*)d_in[3];
    const float* Wk       = (const float*)d_in[4];
    const float* Wv       = (const float*)d_in[5];
    const float* Wb       = (const float*)d_in[6];
    const float* Wg       = (const float*)d_in[7];
    const float* bg       = (const float*)d_in[8];
    const float* Wo       = (const float*)d_in[9];
    const float* bo       = (const float*)d_in[10];
    float* out = (float*)d_out;

    char* ws = (char*)d_ws;
    const size_t MAT = (size_t)NR * CC * sizeof(_Float16);   // 16.78 MB
    _Float16* qh = (_Float16*)ws; ws += MAT;
    _Float16* kh = (_Float16*)ws; ws += MAT;
    _Float16* vh = (_Float16*)ws; ws += MAT;
    _Float16* gh = (_Float16*)ws; ws += MAT;
    _Float16* oh = (_Float16*)ws; ws += MAT;
    float* biasF = (float*)ws;    ws += (size_t)HH * NR * sizeof(float);  // 1 MB
    _Float16* WqT = (_Float16*)ws; ws += 128*128*sizeof(_Float16);
    _Float16* WkT = (_Float16*)ws; ws += 128*128*sizeof(_Float16);
    _Float16* WvT = (_Float16*)ws; ws += 128*128*sizeof(_Float16);
    _Float16* WgT = (_Float16*)ws; ws += 128*128*sizeof(_Float16);
    _Float16* WoT = (_Float16*)ws; ws += 128*128*sizeof(_Float16);
    _Float16* WbT = (_Float16*)ws; ws += 16*128*sizeof(_Float16);

    prep_weights<<<(5*16384 + 16*128 + 255)/256, 256, 0, stream>>>(
        Wq, Wk, Wv, Wg, Wo, Wb, WqT, WkT, WvT, WgT, WoT, WbT);

    proj_kernel<<<NR/16/4, 256, 0, stream>>>(
        pair, ln_scale, ln_bias, WqT, WkT, WvT, WgT, WbT, bg,
        qh, kh, vh, gh, biasF);

    attn_kernel<<<dim3(NN, HH), 256, 0, stream>>>(qh, kh, vh, gh, biasF, oh);

    out_kernel<<<NR/16/4, 256, 0, stream>>>(oh, WoT, bo, out);
}

// Round 4
// 117.461 us; speedup vs baseline: 1.3796x; 1.3796x over previous
//
#include <hip/hip_runtime.h>
#include <hip/hip_bf16.h>

// Triangle attention (start) — N=256, C=128, H=4, D=32, f16 MFMA pipeline.
// R2/R3: single fused per-i mega-kernel. Pre-kernel computes LN->zh(f16) + biasF.
// Mega block (512 thr, one per i): z in regs, per-head K (chunk-swizzled) and
// Vt (padded) in LDS, swapped QK^T (P-row lane-local softmax), PV, gate,
// out-proj, f32 store. Layout transforms via per-wave LDS scratch.

typedef _Float16 half8 __attribute__((ext_vector_type(8)));
typedef _Float16 half4 __attribute__((ext_vector_type(4)));
typedef float floatx4 __attribute__((ext_vector_type(4)));

#define NN 256
#define CC 128
#define HH 4
#define DD 32
#define NR (NN*NN)
#define LN_EPS 1e-5f
#define MFMA(a,b,c) __builtin_amdgcn_mfma_f32_16x16x32_f16(a,b,c,0,0,0)
#define ZERO4 ((floatx4)(0.f))

__device__ inline half4 cvt4(floatx4 v) {
    half4 r; r[0]=(_Float16)v[0]; r[1]=(_Float16)v[1];
    r[2]=(_Float16)v[2]; r[3]=(_Float16)v[3]; return r;
}

// ---------------- Stage 1: weight prep ----------------
__global__ __launch_bounds__(256) void prep_weights(
    const float* __restrict__ Wq, const float* __restrict__ Wk,
    const float* __restrict__ Wv, const float* __restrict__ Wg,
    const float* __restrict__ Wo, const float* __restrict__ Wb,
    _Float16* __restrict__ WqT, _Float16* __restrict__ WkT,
    _Float16* __restrict__ WvT, _Float16* __restrict__ WgT,
    _Float16* __restrict__ WoT, _Float16* __restrict__ WbT)
{
    int id = blockIdx.x * 256 + threadIdx.x;
    if (id < 5 * 16384) {
        int m = id / 16384, e = id % 16384;
        int n = e >> 7, c = e & 127;
        const float* src = (m==0)?Wq:(m==1)?Wk:(m==2)?Wv:(m==3)?Wg:Wo;
        _Float16* dst    = (m==0)?WqT:(m==1)?WkT:(m==2)?WvT:(m==3)?WgT:WoT;
        dst[n*128 + c] = (_Float16)src[c*128 + n];
    } else {
        int e = id - 5*16384;   // WbT padded to [16][128]
        if (e < 16*128) {
            int n = e >> 7, c = e & 127;
            WbT[n*128 + c] = (n < HH) ? (_Float16)Wb[c*HH + n] : (_Float16)0.f;
        }
    }
}

// ---------------- Stage 2: LN -> zh (f16) + pair bias ----------------
__global__ __launch_bounds__(256) void bias_ln_kernel(
    const float* __restrict__ pair, const float* __restrict__ ln_scale,
    const float* __restrict__ ln_bias, const _Float16* __restrict__ WbT,
    _Float16* __restrict__ zh, float* __restrict__ biasF)
{
    int wave = threadIdx.x >> 6, lane = threadIdx.x & 63;
    int mtile = blockIdx.x * 4 + wave;
    int lr = lane & 15, lg = lane >> 4;
    size_t row = (size_t)mtile*16 + lr;

    float xv[4][8];
    float s = 0.f, ss = 0.f;
    #pragma unroll
    for (int ks = 0; ks < 4; ++ks) {
        const float* pr = &pair[row*CC + ks*32 + lg*8];
        float4 a = *(const float4*)pr;
        float4 b = *(const float4*)(pr + 4);
        xv[ks][0]=a.x; xv[ks][1]=a.y; xv[ks][2]=a.z; xv[ks][3]=a.w;
        xv[ks][4]=b.x; xv[ks][5]=b.y; xv[ks][6]=b.z; xv[ks][7]=b.w;
        s  += a.x+a.y+a.z+a.w + b.x+b.y+b.z+b.w;
        ss += a.x*a.x+a.y*a.y+a.z*a.z+a.w*a.w + b.x*b.x+b.y*b.y+b.z*b.z+b.w*b.w;
    }
    s  += __shfl_xor(s, 16);  s  += __shfl_xor(s, 32);
    ss += __shfl_xor(ss, 16); ss += __shfl_xor(ss, 32);
    float mu   = s * (1.f/128.f);
    float var  = ss * (1.f/128.f) - mu*mu;
    float rstd = rsqrtf(var + LN_EPS);

    half8 zfrag[4];
    #pragma unroll
    for (int ks = 0; ks < 4; ++ks) {
        const float* sc = &ln_scale[ks*32 + lg*8];
        const float* bi = &ln_bias[ks*32 + lg*8];
        #pragma unroll
        for (int e = 0; e < 8; ++e)
            zfrag[ks][e] = (_Float16)((xv[ks][e] - mu) * rstd * sc[e] + bi[e]);
        *(half8*)&zh[row*CC + ks*32 + lg*8] = zfrag[ks];
    }

    // bias = z @ Wb  (swapped: lane -> zrow=lr, h = lg*4+r; lg==0 holds h=0..3)
    floatx4 acc2 = ZERO4;
    #pragma unroll
    for (int ks = 0; ks < 4; ++ks) {
        half8 w = *(const half8*)&WbT[lr*128 + ks*32 + lg*8];
        acc2 = MFMA(w, zfrag[ks], acc2);
    }
    if (lg == 0) {
        #pragma unroll
        for (int r = 0; r < 4; ++r)
            biasF[(size_t)r*NR + row] = acc2[r];   // biasF[h][j*256+k]
    }
}

// ---------------- Stage 3: fused per-i mega kernel ----------------
__global__ __launch_bounds__(512, 2) void mega_kernel(
    const _Float16* __restrict__ zh,
    const _Float16* __restrict__ WqT, const _Float16* __restrict__ WkT,
    const _Float16* __restrict__ WvT, const _Float16* __restrict__ WgT,
    const _Float16* __restrict__ WoT,
    const float* __restrict__ bg, const float* __restrict__ biasF,
    const float* __restrict__ bo, float* __restrict__ out)
{
    __shared__ _Float16 Ksm[256*32];     // [k][d], 16B-chunk swizzled: c ^= (k>>1)&3
    __shared__ _Float16 Vt[32*264];      // [d][k], row pad 256->264
    __shared__ _Float16 scr[8*16*96];    // per-wave layout-transform scratch

    const int tid  = threadIdx.x;
    const int wave = tid >> 6, lane = tid & 63;
    const int lr   = lane & 15, lg = lane >> 4;
    const int wbase = wave * 32;                 // this wave's 32 j/z-rows
    const size_t rb = (size_t)blockIdx.x * NN;   // global row base (i*256)
    const int sbase = wave*(16*96) + lr*96;      // scratch row for lane

    // ---- z fragments: [at][ks], layout [zrow=lr][c=lg*8+e] ----
    half8 zf[2][4];
    #pragma unroll
    for (int at = 0; at < 2; ++at)
        #pragma unroll
        for (int ks = 0; ks < 4; ++ks)
            zf[at][ks] = *(const half8*)&zh[(rb + wbase + at*16 + lr)*CC + ks*32 + lg*8];

    half8 ofrag[4][2];   // [h][at] gated attention output fragments

    #pragma unroll
    for (int h = 0; h < HH; ++h) {
        // ---- Q_h (swapped: A=WqT, B=z -> lane: zrow=lr, col=ntl*16+lg*4+r) ----
        half8 qf[2];
        #pragma unroll
        for (int at = 0; at < 2; ++at) {
            floatx4 qa[2];
            #pragma unroll
            for (int ntl = 0; ntl < 2; ++ntl) {
                floatx4 a = ZERO4;
                #pragma unroll
                for (int ks = 0; ks < 4; ++ks)
                    a = MFMA(*(const half8*)&WqT[((2*h+ntl)*16 + lr)*CC + ks*32 + lg*8],
                             zf[at][ks], a);
                qa[ntl] = a * 0.17677669529663687f;   // 1/sqrt(32)
            }
            int sb = sbase + (at&1)*48;
            *(half4*)&scr[sb + lg*4]      = cvt4(qa[0]);
            *(half4*)&scr[sb + 16 + lg*4] = cvt4(qa[1]);
            qf[at] = *(const half8*)&scr[sb + lg*8];  // [j=lr][d=lg*8+e]
        }

        // ---- gate_h ----
        half4 gt[2][2];
        #pragma unroll
        for (int at = 0; at < 2; ++at)
            #pragma unroll
            for (int ntl = 0; ntl < 2; ++ntl) {
                floatx4 a = ZERO4;
                #pragma unroll
                for (int ks = 0; ks < 4; ++ks)
                    a = MFMA(*(const half8*)&WgT[((2*h+ntl)*16 + lr)*CC + ks*32 + lg*8],
                             zf[at][ks], a);
                floatx4 b4 = *(const floatx4*)&bg[(2*h+ntl)*16 + lg*4];
                half4 g4;
                #pragma unroll
                for (int r = 0; r < 4; ++r)
                    g4[r] = (_Float16)(1.f/(1.f + __expf(-(a[r] + b4[r]))));
                gt[at][ntl] = g4;
            }

        __syncthreads();   // previous head's readers done with Ksm/Vt

        // ---- K_h -> Ksm (swapped; lane: k=zrow=lr(+tile), 4 consecutive d) ----
        #pragma unroll
        for (int at = 0; at < 2; ++at) {
            int kk = wbase + at*16 + lr;
            int swz = (kk >> 1) & 3;
            #pragma unroll
            for (int ntl = 0; ntl < 2; ++ntl) {
                floatx4 a = ZERO4;
                #pragma unroll
                for (int ks = 0; ks < 4; ++ks)
                    a = MFMA(*(const half8*)&WkT[((2*h+ntl)*16 + lr)*CC + ks*32 + lg*8],
                             zf[at][ks], a);
                int chunk = ntl*2 + (lg>>1);          // d>>3
                *(half4*)&Ksm[(kk*4 + (chunk ^ swz))*8 + (lg&1)*4] = cvt4(a);
            }
        }
        // ---- V_h -> Vt (unswapped; lane: d=ntl*16+lr, 4 consecutive k-rows) ----
        #pragma unroll
        for (int at = 0; at < 2; ++at) {
            int k0 = wbase + at*16 + lg*4;
            #pragma unroll
            for (int ntl = 0; ntl < 2; ++ntl) {
                floatx4 a = ZERO4;
                #pragma unroll
                for (int ks = 0; ks < 4; ++ks)
                    a = MFMA(zf[at][ks],
                             *(const half8*)&WvT[((2*h+ntl)*16 + lr)*CC + ks*32 + lg*8], a);
                int d = ntl*16 + lr;
                *(half4*)&Vt[d*264 + k0] = cvt4(a);
            }
        }

        __syncthreads();   // K/V visible to all waves

        // ---- attention for this head, per 16-row j-tile ----
        #pragma unroll
        for (int at = 0; at < 2; ++at) {
            int j = wbase + at*16 + lr;
            // S = K·Q^T (swapped): lane: j=lr, k = nt*16+lg*4+r
            floatx4 sacc[16];
            #pragma unroll
            for (int nt = 0; nt < 16; ++nt) {
                int kk = nt*16 + lr;
                half8 kf = *(const half8*)&Ksm[(kk*4 + (lg ^ ((kk>>1)&3)))*8];
                floatx4 a = MFMA(kf, qf[at], ZERO4);
                a += *(const floatx4*)&biasF[((size_t)h*NN + j)*NN + nt*16 + lg*4];
                sacc[nt] = a;
            }
            // softmax over k: in-lane 64 + 2 shfls (row spread over 4 lg-lanes)
            float m = -1e30f;
            #pragma unroll
            for (int nt = 0; nt < 16; ++nt)
                #pragma unroll
                for (int r = 0; r < 4; ++r) m = fmaxf(m, sacc[nt][r]);
            m = fmaxf(m, __shfl_xor(m, 16));
            m = fmaxf(m, __shfl_xor(m, 32));
            float l = 0.f;
            #pragma unroll
            for (int nt = 0; nt < 16; ++nt)
                #pragma unroll
                for (int r = 0; r < 4; ++r) {
                    float p = __expf(sacc[nt][r] - m);
                    sacc[nt][r] = p; l += p;
                }
            l += __shfl_xor(l, 16);
            l += __shfl_xor(l, 32);
            float linv = 1.f / l;

            // PV: per 32-k group: P->f16 frag via scratch, 2 MFMA (A=Vt, B=P)
            floatx4 oacc0 = ZERO4;
            floatx4 oacc1 = ZERO4;
            #pragma unroll
            for (int g = 0; g < 8; ++g) {
                int sb = sbase + (g&1)*48;
                *(half4*)&scr[sb + lg*4]      = cvt4(sacc[2*g]);
                *(half4*)&scr[sb + 16 + lg*4] = cvt4(sacc[2*g+1]);
                half8 pf = *(const half8*)&scr[sb + lg*8];   // [j=lr][k=g*32+lg*8+e]
                half8 vf0 = *(const half8*)&Vt[(lr)*264      + g*32 + lg*8];
                half8 vf1 = *(const half8*)&Vt[(16+lr)*264   + g*32 + lg*8];
                oacc0 = MFMA(vf0, pf, oacc0);
                oacc1 = MFMA(vf1, pf, oacc1);
            }
            // normalize, gate, pack -> ofrag[h][at] via scratch (parity 0)
            half4 pk0, pk1;
            #pragma unroll
            for (int r = 0; r < 4; ++r) {
                pk0[r] = (_Float16)(oacc0[r] * linv * (float)gt[at][0][r]);
                pk1[r] = (_Float16)(oacc1[r] * linv * (float)gt[at][1][r]);
            }
            *(half4*)&scr[sbase + lg*4]      = pk0;
            *(half4*)&scr[sbase + 16 + lg*4] = pk1;
            ofrag[h][at] = *(const half8*)&scr[sbase + lg*8];  // [j=lr][c=h*32+lg*8+e]
        }
    }

    // ---- out projection: A=WoT, B=ofrag -> lane: j=lr, 4 consecutive cols ----
    #pragma unroll
    for (int at = 0; at < 2; ++at) {
        size_t orow = rb + wbase + at*16 + lr;
        #pragma unroll
        for (int nt = 0; nt < 8; ++nt) {
            floatx4 a = ZERO4;
            #pragma unroll
            for (int ks = 0; ks < 4; ++ks)
                a = MFMA(*(const half8*)&WoT[(nt*16 + lr)*CC + ks*32 + lg*8],
                         ofrag[ks][at], a);
            int col = nt*16 + lg*4;
            a += *(const floatx4*)&bo[col];
            *(floatx4*)&out[orow*CC + col] = a;
        }
    }
}

// ---------------- launch ----------------
extern "C" void kernel_launch(void* const* d_in, const int* in_sizes, int n_in,
                              void* d_out, int out_size, void* d_ws, size_t ws_size,
                              hipStream_t stream)
{
    const float* pair     = (const float*)d_in[0];
    const float* ln_scale = (const float*)d_in[1];
    const float* ln_bias  = (const float*)d_in[2];
    const float* Wq       = (const float*)d_in[3];
    const float* Wk       = (const float*)d_in[4];
    const float* Wv       = (const float*)d_in[5];
    const float* Wb       = (const float*)d_in[6];
    const float* Wg       = (const float*)d_in[7];
    const float* bg       = (const float*)d_in[8];
    const float* Wo       = (const float*)d_in[9];
    const float* bo       = (const float*)d_in[10];
    float* out = (float*)d_out;

    char* ws = (char*)d_ws;
    _Float16* zh  = (_Float16*)ws; ws += (size_t)NR * CC * sizeof(_Float16); // 16.78 MB
    float* biasF  = (float*)ws;    ws += (size_t)HH * NR * sizeof(float);    // 1 MB
    _Float16* WqT = (_Float16*)ws; ws += 128*128*sizeof(_Float16);
    _Float16* WkT = (_Float16*)ws; ws += 128*128*sizeof(_Float16);
    _Float16* WvT = (_Float16*)ws; ws += 128*128*sizeof(_Float16);
    _Float16* WgT = (_Float16*)ws; ws += 128*128*sizeof(_Float16);
    _Float16* WoT = (_Float16*)ws; ws += 128*128*sizeof(_Float16);
    _Float16* WbT = (_Float16*)ws; ws += 16*128*sizeof(_Float16);

    prep_weights<<<(5*16384 + 16*128 + 255)/256, 256, 0, stream>>>(
        Wq, Wk, Wv, Wg, Wo, Wb, WqT, WkT, WvT, WgT, WoT, WbT);

    bias_ln_kernel<<<NR/16/4, 256, 0, stream>>>(
        pair, ln_scale, ln_bias, WbT, zh, biasF);

    mega_kernel<<<NN, 512, 0, stream>>>(
        zh, WqT, WkT, WvT, WgT, WoT, bg, biasF, bo, out);
}